// Round 1
// baseline (13230.133 us; speedup 1.0000x reference)
//
#include <hip/hip_runtime.h>
#include <stdint.h>

#define T_ 1024
#define B_ 64
#define I_ 256
#define H_ 512
#define O_ 5
#define NB 16            // batches per chain
#define NCHAIN 4
#define JW 16            // hidden columns per WG
#define WGC 32           // WGs per chain (512/16)
#define GRID_MAIN (NCHAIN*WGC)   // 128
#define BLOCK_MAIN 256
#define XH_STRIDE 776    // 768 + 8 pad (breaks LDS bank aliasing)
#define HS_OFF 4096
#define TBO (T_*B_*O_)
#define BH (B_*H_)

typedef __bf16 bf16x8 __attribute__((ext_vector_type(8)));
typedef float floatx4 __attribute__((ext_vector_type(4)));
typedef unsigned short u16;
typedef unsigned short u16x8 __attribute__((ext_vector_type(8)));

__device__ __forceinline__ u16 f2bf(float f) {
  unsigned int u = __float_as_uint(f);
  u += 0x7fffu + ((u >> 16) & 1u);   // RNE
  return (u16)(u >> 16);
}
__device__ __forceinline__ float bf2f(u16 v) {
  return __uint_as_float(((unsigned int)v) << 16);
}
__device__ __forceinline__ float sigmoid_f(float x) {
  return 1.0f / (1.0f + __expf(-x));
}
__device__ __forceinline__ float tanh_f(float x) {
  return 2.0f / (1.0f + __expf(-2.0f * x)) - 1.0f;
}

// Persistent LSTM kernel. 4 independent chains (16 batches each), 32 WGs/chain.
// WG: 16 j's x 4 gates x 16 batches. Wave w handles K-range [w*192,(w+1)*192)
// over all 4 gate tiles (split-K => each B-frag feeds 4 MFMAs).
// W held in registers as bf16 MFMA A-fragments for the whole kernel.
__global__ __launch_bounds__(BLOCK_MAIN, 1)
void lstm_persistent(const float* __restrict__ x,
                     const float* __restrict__ W_ih,
                     const float* __restrict__ W_hh,
                     const float* __restrict__ b_ih,
                     const float* __restrict__ b_hh,
                     float* __restrict__ out,
                     unsigned int* __restrict__ counters,
                     u16* __restrict__ hs)
{
  __shared__ __align__(16) u16 xh[NB * XH_STRIDE];        // [b][k] k in [0,768)
  __shared__ float part[4 * 4 * 16 * 17];                 // [w][gate][jl][b(+pad)]

  const int tid   = threadIdx.x;
  const int wg    = blockIdx.x;
  const int chain = wg >> 5;
  const int jbase = (wg & 31) * JW;
  const int bbase = chain * NB;
  const int w     = tid >> 6;       // wave id = K-quarter
  const int lane  = tid & 63;
  const int q     = lane >> 4;
  const int n     = lane & 15;

  // ---- W -> register A-fragments (A[m=lane&15][k=q*8+i]), once ----
  bf16x8 afrag[4][6];
  #pragma unroll
  for (int g = 0; g < 4; ++g) {
    #pragma unroll
    for (int kk = 0; kk < 6; ++kk) {
      const int kc  = w * 6 + kk;                 // K-chunk of 32
      const int row = g * H_ + jbase + n;         // gate row in [0,2048)
      const float* src;
      if (kc < 8) src = W_ih + (size_t)row * I_ + kc * 32 + q * 8;
      else        src = W_hh + (size_t)row * H_ + (kc - 8) * 32 + q * 8;
      float4 f0 = ((const float4*)src)[0];
      float4 f1 = ((const float4*)src)[1];
      bf16x8 a;
      a[0]=(__bf16)f0.x; a[1]=(__bf16)f0.y; a[2]=(__bf16)f0.z; a[3]=(__bf16)f0.w;
      a[4]=(__bf16)f1.x; a[5]=(__bf16)f1.y; a[6]=(__bf16)f1.z; a[7]=(__bf16)f1.w;
      afrag[g][kk] = a;
    }
  }

  // ---- per-thread elementwise identity: (eb, ej) ----
  const int eb = tid >> 4;   // batch within chain
  const int ej = tid & 15;   // j within WG
  float bias[4];
  #pragma unroll
  for (int g = 0; g < 4; ++g) {
    const int row = g * H_ + jbase + ej;
    bias[g] = b_ih[row] + b_hh[row];
  }
  float cval = 0.0f;

  unsigned int* cnt = counters + chain * 64;   // 256B apart per chain

  for (int t = 0; t < T_; ++t) {
    // wait: hs slot t (= h_{t-1}) complete chain-wide
    const unsigned int target = 32u * (unsigned int)t;
    while (__hip_atomic_load(cnt, __ATOMIC_ACQUIRE, __HIP_MEMORY_SCOPE_AGENT) < target)
      __builtin_amdgcn_s_sleep(1);

    // stage xh = [bf16(x_t) | h_{t-1}] for our 16 batches (24 KB)
    {
      const float* xbase = x + ((size_t)t * B_ + bbase) * I_;
      const u16*   hbase = hs + (size_t)t * BH + (size_t)bbase * H_;
      #pragma unroll
      for (int ci = 0; ci < 6; ++ci) {
        int cid = tid + 256 * ci;    // 1536 chunks of 8 elems
        if (cid < 512) {             // x part: 16 rows x 32 chunks
          int b  = cid >> 5;
          int ko = (cid & 31) * 8;
          const float4* s = (const float4*)(xbase + (size_t)b * I_ + ko);
          float4 f0 = s[0], f1 = s[1];
          u16x8 u;
          u[0]=f2bf(f0.x); u[1]=f2bf(f0.y); u[2]=f2bf(f0.z); u[3]=f2bf(f0.w);
          u[4]=f2bf(f1.x); u[5]=f2bf(f1.y); u[6]=f2bf(f1.z); u[7]=f2bf(f1.w);
          *(u16x8*)&xh[b * XH_STRIDE + ko] = u;
        } else {                     // h part: 16 rows x 64 chunks
          int cid2 = cid - 512;
          int b  = cid2 >> 6;
          int ko = (cid2 & 63) * 8;
          uint4 v = *(const uint4*)(hbase + (size_t)b * H_ + ko);
          *(uint4*)&xh[b * XH_STRIDE + 256 + ko] = v;
        }
      }
    }
    __syncthreads();

    // MFMA partial gates over this wave's K-quarter
    floatx4 acc[4] = {};
    #pragma unroll
    for (int kk = 0; kk < 6; ++kk) {
      const int kc = w * 6 + kk;
      bf16x8 bfrag = __builtin_bit_cast(bf16x8,
          *(const uint4*)&xh[n * XH_STRIDE + kc * 32 + q * 8]);
      #pragma unroll
      for (int g = 0; g < 4; ++g)
        acc[g] = __builtin_amdgcn_mfma_f32_16x16x32_bf16(afrag[g][kk], bfrag, acc[g], 0, 0, 0);
    }

    // write partial C tiles (C: col=lane&15, row=q*4+reg)
    #pragma unroll
    for (int g = 0; g < 4; ++g)
      #pragma unroll
      for (int r = 0; r < 4; ++r)
        part[((w * 4 + g) * 16 + (q * 4 + r)) * 17 + n] = acc[g][r];
    __syncthreads();

    // elementwise: reduce 4 K-partials, gates -> c,h
    {
      float gate[4];
      #pragma unroll
      for (int g = 0; g < 4; ++g) {
        float s = bias[g];
        #pragma unroll
        for (int w2 = 0; w2 < 4; ++w2)
          s += part[((w2 * 4 + g) * 16 + ej) * 17 + eb];
        gate[g] = s;
      }
      const float ig = sigmoid_f(gate[0]);
      const float fg = sigmoid_f(gate[1]);
      const float gg = tanh_f(gate[2]);
      const float og = sigmoid_f(gate[3]);
      cval = fg * cval + ig * gg;
      const float hval = og * tanh_f(cval);
      const int bg = bbase + eb;
      const int jg = jbase + ej;
      hs[(size_t)(t + 1) * BH + (size_t)bg * H_ + jg] = f2bf(hval);
      if (t == T_ - 1) {
        out[TBO + (size_t)bg * H_ + jg]      = hval;   // h_T
        out[TBO + BH + (size_t)bg * H_ + jg] = cval;   // c_T
      }
    }
    __syncthreads();
    if (tid == 0)
      __hip_atomic_fetch_add(cnt, 1u, __ATOMIC_RELEASE, __HIP_MEMORY_SCOPE_AGENT);
  }
}

// outputs[t,b,:] = h_t @ fc_w^T + fc_b ; one wave per (t,b) row
__global__ __launch_bounds__(256)
void fc_kernel(const u16* __restrict__ hs,
               const float* __restrict__ fc_w,
               const float* __restrict__ fc_b,
               float* __restrict__ out)
{
  const int gw   = (blockIdx.x * 256 + threadIdx.x) >> 6;
  const int lane = threadIdx.x & 63;
  const int t = gw >> 6;
  const int b = gw & 63;
  const u16* hrow = hs + ((size_t)(t + 1) * B_ + b) * H_ + lane * 8;
  uint4 hv = *(const uint4*)hrow;
  float h[8];
  {
    u16x8 hu = __builtin_bit_cast(u16x8, hv);
    #pragma unroll
    for (int i = 0; i < 8; ++i) h[i] = bf2f(hu[i]);
  }
  float accs[O_];
  #pragma unroll
  for (int o = 0; o < O_; ++o) {
    const float* wr = fc_w + (size_t)o * H_ + lane * 8;
    float4 w0 = ((const float4*)wr)[0];
    float4 w1 = ((const float4*)wr)[1];
    accs[o] = h[0]*w0.x + h[1]*w0.y + h[2]*w0.z + h[3]*w0.w
            + h[4]*w1.x + h[5]*w1.y + h[6]*w1.z + h[7]*w1.w;
  }
  #pragma unroll
  for (int o = 0; o < O_; ++o)
    #pragma unroll
    for (int off = 32; off > 0; off >>= 1)
      accs[o] += __shfl_down(accs[o], off, 64);
  if (lane == 0) {
    #pragma unroll
    for (int o = 0; o < O_; ++o)
      out[((size_t)t * B_ + b) * O_ + o] = accs[o] + fc_b[o];
  }
}

extern "C" void kernel_launch(void* const* d_in, const int* in_sizes, int n_in,
                              void* d_out, int out_size, void* d_ws, size_t ws_size,
                              hipStream_t stream)
{
  const float* x    = (const float*)d_in[0];
  const float* W_ih = (const float*)d_in[1];
  const float* W_hh = (const float*)d_in[2];
  const float* b_ih = (const float*)d_in[3];
  const float* b_hh = (const float*)d_in[4];
  const float* fc_w = (const float*)d_in[5];
  const float* fc_b = (const float*)d_in[6];
  float* out = (float*)d_out;

  unsigned int* counters = (unsigned int*)d_ws;
  u16* hs = (u16*)((char*)d_ws + HS_OFF);   // (T_+1) * B_*H_ bf16 (~64 MB)

  hipMemsetAsync(d_ws, 0, HS_OFF, stream);           // chain counters = 0
  hipMemsetAsync(hs, 0, (size_t)BH * 2, stream);     // h_{-1} = 0

  lstm_persistent<<<GRID_MAIN, BLOCK_MAIN, 0, stream>>>(
      x, W_ih, W_hh, b_ih, b_hh, out, counters, hs);
  fc_kernel<<<(T_ * B_) / 4, 256, 0, stream>>>(hs, fc_w, fc_b, out);
}

// Round 2
// 4085.328 us; speedup vs baseline: 3.2385x; 3.2385x over previous
//
#include <hip/hip_runtime.h>
#include <stdint.h>

#define T_ 1024
#define B_ 64
#define I_ 256
#define H_ 512
#define O_ 5
#define NB 16            // batches per chain
#define NCHAIN 4
#define JW 16            // hidden columns per WG
#define WGC 32           // WGs per chain (512/16)
#define GRID_MAIN (NCHAIN*WGC)   // 128
#define BLOCK_MAIN 256
#define XH_STRIDE 776    // 768 + 8 pad (breaks LDS bank aliasing)
#define HS_OFF 4096
#define TBO (T_*B_*O_)
#define BH (B_*H_)

typedef __bf16 bf16x8 __attribute__((ext_vector_type(8)));
typedef float floatx4 __attribute__((ext_vector_type(4)));
typedef unsigned short u16;
typedef unsigned short u16x8 __attribute__((ext_vector_type(8)));
typedef unsigned long long u64;

__device__ __forceinline__ u16 f2bf(float f) {
  unsigned int u = __float_as_uint(f);
  u += 0x7fffu + ((u >> 16) & 1u);   // RNE
  return (u16)(u >> 16);
}
__device__ __forceinline__ float bf2f(u16 v) {
  return __uint_as_float(((unsigned int)v) << 16);
}
__device__ __forceinline__ float sigmoid_f(float x) {
  return 1.0f / (1.0f + __expf(-x));
}
__device__ __forceinline__ float tanh_f(float x) {
  return 2.0f / (1.0f + __expf(-2.0f * x)) - 1.0f;
}

// Persistent LSTM. 4 chains (16 batches each), 32 WGs/chain; W register-resident
// as bf16 MFMA A-fragments. Cross-WG h exchange via L3-coherent relaxed
// agent-scope accesses (sc0|sc1) — NO acquire/release fences in the T-loop
// (those lower to buffer_inv/buffer_wbl2 = bulk L2 maintenance, which was the
// 13 µs/step killer in R1). Per-WG flag words (no RMW contention); ordering =
// pre-barrier vmcnt drain of sc1 write-through stores.
__global__ __launch_bounds__(BLOCK_MAIN, 1)
void lstm_persistent(const float* __restrict__ x,
                     const float* __restrict__ W_ih,
                     const float* __restrict__ W_hh,
                     const float* __restrict__ b_ih,
                     const float* __restrict__ b_hh,
                     float* __restrict__ out,
                     unsigned int* __restrict__ flagbase,
                     u16* __restrict__ hs)
{
  __shared__ __align__(16) u16 xh[NB * XH_STRIDE];        // [b][k] k in [0,768)
  __shared__ float part[4 * 4 * 16 * 17];                 // [w][gate][jl][b(+pad)]

  const int tid   = threadIdx.x;
  const int wg    = blockIdx.x;
  const int chain = wg >> 5;
  const int jbase = (wg & 31) * JW;
  const int bbase = chain * NB;
  const int w     = tid >> 6;       // wave id = K-quarter
  const int lane  = tid & 63;
  const int q     = lane >> 4;
  const int n     = lane & 15;

  // ---- W -> register A-fragments (A[m=lane&15][k=q*8+i]), once ----
  bf16x8 afrag[4][6];
  #pragma unroll
  for (int g = 0; g < 4; ++g) {
    #pragma unroll
    for (int kk = 0; kk < 6; ++kk) {
      const int kc  = w * 6 + kk;                 // K-chunk of 32
      const int row = g * H_ + jbase + n;         // gate row in [0,2048)
      const float* src;
      if (kc < 8) src = W_ih + (size_t)row * I_ + kc * 32 + q * 8;
      else        src = W_hh + (size_t)row * H_ + (kc - 8) * 32 + q * 8;
      float4 f0 = ((const float4*)src)[0];
      float4 f1 = ((const float4*)src)[1];
      bf16x8 a;
      a[0]=(__bf16)f0.x; a[1]=(__bf16)f0.y; a[2]=(__bf16)f0.z; a[3]=(__bf16)f0.w;
      a[4]=(__bf16)f1.x; a[5]=(__bf16)f1.y; a[6]=(__bf16)f1.z; a[7]=(__bf16)f1.w;
      afrag[g][kk] = a;
    }
  }

  // ---- elementwise identity: threads 0..127 each own (eb, j0..j0+1) ----
  const int eb = tid >> 3;          // batch within chain (0..15)
  const int j0 = (tid & 7) * 2;     // j pair within WG
  float bias2[2][4];
  float c2[2] = {0.0f, 0.0f};
  if (tid < 128) {
    #pragma unroll
    for (int jj = 0; jj < 2; ++jj)
      #pragma unroll
      for (int g = 0; g < 4; ++g) {
        const int row = g * H_ + jbase + j0 + jj;
        bias2[jj][g] = b_ih[row] + b_hh[row];
      }
  }

  unsigned int* flags = flagbase + chain * 64;   // 32 words used, 256B apart
  const int mywg = wg & 31;

  for (int t = 0; t < T_; ++t) {
    // ---- wait for h_{t-1} chain-wide: wave0 polls, relaxed (no L2 inv) ----
    if (tid < 64) {
      const unsigned int tgt = (unsigned int)t;
      while (true) {
        unsigned int f = __hip_atomic_load(&flags[tid & 31],
                                           __ATOMIC_RELAXED, __HIP_MEMORY_SCOPE_AGENT);
        if (__all((int)(f >= tgt))) break;
        __builtin_amdgcn_s_sleep(2);
      }
    }
    __syncthreads();

    // ---- stage xh = [bf16(x_t) | h_{t-1}] for our 16 batches (24 KB) ----
    {
      const float* xbase = x + ((size_t)t * B_ + bbase) * I_;
      u16* hbase = hs + (size_t)t * BH + (size_t)bbase * H_;
      #pragma unroll
      for (int ci = 0; ci < 6; ++ci) {
        int cid = tid + 256 * ci;    // 512 x-chunks(32B) + 1024 h-chunks(16B)
        if (cid < 512) {             // x: 16 rows x 32 chunks of 8 floats
          int b  = cid >> 5;
          int ko = (cid & 31) * 8;
          const float4* s = (const float4*)(xbase + (size_t)b * I_ + ko);
          float4 f0 = s[0], f1 = s[1];
          u16x8 u;
          u[0]=f2bf(f0.x); u[1]=f2bf(f0.y); u[2]=f2bf(f0.z); u[3]=f2bf(f0.w);
          u[4]=f2bf(f1.x); u[5]=f2bf(f1.y); u[6]=f2bf(f1.z); u[7]=f2bf(f1.w);
          *(u16x8*)&xh[b * XH_STRIDE + ko] = u;
        } else {                     // h: 16 rows x 64 chunks of 8 u16 (L3-coherent)
          int hc = cid - 512;
          int b  = hc >> 6;
          int ko = (hc & 63) * 8;
          u64 h0 = __hip_atomic_load((u64*)(hbase + (size_t)b * H_ + ko),
                                     __ATOMIC_RELAXED, __HIP_MEMORY_SCOPE_AGENT);
          u64 h1 = __hip_atomic_load((u64*)(hbase + (size_t)b * H_ + ko + 4),
                                     __ATOMIC_RELAXED, __HIP_MEMORY_SCOPE_AGENT);
          *(u64*)&xh[b * XH_STRIDE + 256 + ko]     = h0;
          *(u64*)&xh[b * XH_STRIDE + 256 + ko + 4] = h1;
        }
      }
    }
    __syncthreads();

    // ---- MFMA partial gates over this wave's K-quarter ----
    floatx4 acc[4] = {};
    #pragma unroll
    for (int kk = 0; kk < 6; ++kk) {
      const int kc = w * 6 + kk;
      bf16x8 bfrag = __builtin_bit_cast(bf16x8,
          *(const uint4*)&xh[n * XH_STRIDE + kc * 32 + q * 8]);
      #pragma unroll
      for (int g = 0; g < 4; ++g)
        acc[g] = __builtin_amdgcn_mfma_f32_16x16x32_bf16(afrag[g][kk], bfrag, acc[g], 0, 0, 0);
    }

    // write partial C tiles (C: col=lane&15, row=q*4+reg)
    #pragma unroll
    for (int g = 0; g < 4; ++g)
      #pragma unroll
      for (int r = 0; r < 4; ++r)
        part[((w * 4 + g) * 16 + (q * 4 + r)) * 17 + n] = acc[g][r];
    __syncthreads();

    // ---- elementwise: reduce 4 K-partials, gates -> c,h ; publish h ----
    if (tid < 128) {
      float hv2[2];
      #pragma unroll
      for (int jj = 0; jj < 2; ++jj) {
        float gate[4];
        #pragma unroll
        for (int g = 0; g < 4; ++g) {
          float s = bias2[jj][g];
          #pragma unroll
          for (int w2 = 0; w2 < 4; ++w2)
            s += part[((w2 * 4 + g) * 16 + (j0 + jj)) * 17 + eb];
          gate[g] = s;
        }
        const float ig = sigmoid_f(gate[0]);
        const float fg = sigmoid_f(gate[1]);
        const float gg = tanh_f(gate[2]);
        const float og = sigmoid_f(gate[3]);
        c2[jj] = fg * c2[jj] + ig * gg;
        hv2[jj] = og * tanh_f(c2[jj]);
      }
      const int bg = bbase + eb;
      const int jg = jbase + j0;
      unsigned int packed = (unsigned int)f2bf(hv2[0]) |
                            ((unsigned int)f2bf(hv2[1]) << 16);
      __hip_atomic_store((unsigned int*)(hs + (size_t)(t + 1) * BH +
                                         (size_t)bg * H_ + jg),
                         packed, __ATOMIC_RELAXED, __HIP_MEMORY_SCOPE_AGENT);
      if (t == T_ - 1) {
        out[TBO + (size_t)bg * H_ + jg]          = hv2[0];   // h_T
        out[TBO + (size_t)bg * H_ + jg + 1]      = hv2[1];
        out[TBO + BH + (size_t)bg * H_ + jg]     = c2[0];    // c_T
        out[TBO + BH + (size_t)bg * H_ + jg + 1] = c2[1];
      }
    }
    // barrier drains every wave's vmcnt (sc1 stores at coherence point)
    __syncthreads();
    if (tid == 0)
      __hip_atomic_store(&flags[mywg], (unsigned int)(t + 1),
                         __ATOMIC_RELAXED, __HIP_MEMORY_SCOPE_AGENT);
  }
}

// outputs[t,b,:] = h_t @ fc_w^T + fc_b ; one wave per (t,b) row
__global__ __launch_bounds__(256)
void fc_kernel(const u16* __restrict__ hs,
               const float* __restrict__ fc_w,
               const float* __restrict__ fc_b,
               float* __restrict__ out)
{
  const int gw   = (blockIdx.x * 256 + threadIdx.x) >> 6;
  const int lane = threadIdx.x & 63;
  const int t = gw >> 6;
  const int b = gw & 63;
  const u16* hrow = hs + ((size_t)(t + 1) * B_ + b) * H_ + lane * 8;
  uint4 hv = *(const uint4*)hrow;
  float h[8];
  {
    u16x8 hu = __builtin_bit_cast(u16x8, hv);
    #pragma unroll
    for (int i = 0; i < 8; ++i) h[i] = bf2f(hu[i]);
  }
  float accs[O_];
  #pragma unroll
  for (int o = 0; o < O_; ++o) {
    const float* wr = fc_w + (size_t)o * H_ + lane * 8;
    float4 w0 = ((const float4*)wr)[0];
    float4 w1 = ((const float4*)wr)[1];
    accs[o] = h[0]*w0.x + h[1]*w0.y + h[2]*w0.z + h[3]*w0.w
            + h[4]*w1.x + h[5]*w1.y + h[6]*w1.z + h[7]*w1.w;
  }
  #pragma unroll
  for (int o = 0; o < O_; ++o)
    #pragma unroll
    for (int off = 32; off > 0; off >>= 1)
      accs[o] += __shfl_down(accs[o], off, 64);
  if (lane == 0) {
    #pragma unroll
    for (int o = 0; o < O_; ++o)
      out[((size_t)t * B_ + b) * O_ + o] = accs[o] + fc_b[o];
  }
}

extern "C" void kernel_launch(void* const* d_in, const int* in_sizes, int n_in,
                              void* d_out, int out_size, void* d_ws, size_t ws_size,
                              hipStream_t stream)
{
  const float* x    = (const float*)d_in[0];
  const float* W_ih = (const float*)d_in[1];
  const float* W_hh = (const float*)d_in[2];
  const float* b_ih = (const float*)d_in[3];
  const float* b_hh = (const float*)d_in[4];
  const float* fc_w = (const float*)d_in[5];
  const float* fc_b = (const float*)d_in[6];
  float* out = (float*)d_out;

  unsigned int* flags = (unsigned int*)d_ws;
  u16* hs = (u16*)((char*)d_ws + HS_OFF);   // (T_+1) * B_*H_ bf16 (~64 MB)

  hipMemsetAsync(d_ws, 0, HS_OFF, stream);           // chain flags = 0
  hipMemsetAsync(hs, 0, (size_t)BH * 2, stream);     // h_{-1} = 0

  lstm_persistent<<<GRID_MAIN, BLOCK_MAIN, 0, stream>>>(
      x, W_ih, W_hh, b_ih, b_hh, out, flags, hs);
  fc_kernel<<<(T_ * B_) / 4, 256, 0, stream>>>(hs, fc_w, fc_b, out);
}